// Round 6
// baseline (421.134 us; speedup 1.0000x reference)
//
#include <hip/hip_runtime.h>
#include <hip/hip_cooperative_groups.h>
#include <cstdint>

namespace cg = cooperative_groups;

#define N_NODES 50000
#define N_EDGES 800000
#define N_FEAT 256
#define HIDDEN 128
#define N_CLASSES 40
#define NB_NODES 196        // ceil(50000/256)
#define NBUCKET 196         // dst >> 8
#define EPB 3125            // edges per hist/partition block (256 * 3125 = 800000)
#define ROWS_PAD 50048      // 782 * 64
#define H2S 64              // h2 row stride (ushorts) = 128 B aligned

typedef __attribute__((ext_vector_type(8))) short bf16x8;
typedef __attribute__((ext_vector_type(4))) float f32x4;

__device__ inline ushort f2bf(float f) {
    union { float f; uint u; } v; v.f = f;
    uint u = v.u;
    u += 0x7fff + ((u >> 16) & 1);   // round-to-nearest-even
    return (ushort)(u >> 16);
}
__device__ inline float bflo(uint u) {
    union { uint u; float f; } v; v.u = u << 16; return v.f;
}
__device__ inline float bfhi(uint u) {
    union { uint u; float f; } v; v.u = u & 0xffff0000u; return v.f;
}

// ================= fused preprocessing (single cooperative kernel) =================
// grid = 256 blocks x 256 threads. Phases separated by grid.sync():
//   P0 repack W1/W2 + per-block bucket histogram
//   P1 scanA histT -> poff (inclusive per 256-chunk) + bsumA
//   P2 scanC: exclusive fixup (each block redundantly scans bsumA in LDS)
//   P3 partition edges -> ebuf (bucket-grouped, packed dst<<16|src)
//   P4 per-bucket degree + dinv
//   P5 scanA deg -> rowptr + bsumB
//   P6 scanC fixup -> exclusive rowptr
//   P7 per-bucket CSR fill -> esrc

struct PP {
    const int* src; const int* dst;
    const float* W1; const float* W2;
    ushort* Bp1; ushort* Bp2;
    int* histT; int* poff; int* bsumA;
    uint* ebuf; int* deg; float* dinv;
    int* rowptr; int* bsumB; int* esrc;
};

__device__ void block_scan_chunk(const int* in, int* incl, int* bsum, int n, int* sh) {
    // chunk = blockIdx.x (must be < 196); Hillis-Steele inclusive scan of 256 elems
    int blk = blockIdx.x, t = threadIdx.x;
    int i = blk * 256 + t;
    int v = (i < n) ? in[i] : 0;
    sh[t] = v;
    __syncthreads();
    for (int off = 1; off < 256; off <<= 1) {
        int t2 = 0;
        if (t >= off) t2 = sh[t - off];
        __syncthreads();
        sh[t] += t2;
        __syncthreads();
    }
    incl[i] = sh[t];
    if (t == 255) bsum[blk] = sh[255];
}

__device__ void block_scan_fixup(const int* in, int* incl, const int* bsum, int* sh) {
    // exclusive fixup; each block redundantly scans bsum[0..195] in LDS
    int blk = blockIdx.x, t = threadIdx.x;
    sh[t] = (t < NBUCKET) ? bsum[t] : 0;
    __syncthreads();
    for (int off = 1; off < 256; off <<= 1) {
        int t2 = 0;
        if (t >= off) t2 = sh[t - off];
        __syncthreads();
        sh[t] += t2;
        __syncthreads();
    }
    int base = (blk > 0) ? sh[blk - 1] : 0;
    int i = blk * 256 + t;
    incl[i] = incl[i] - in[i] + base;
    __syncthreads();
}

__global__ __launch_bounds__(256) void preprocess(PP p) {
    __shared__ int sh[512];
    cg::grid_group grid = cg::this_grid();
    int blk = blockIdx.x, t = threadIdx.x;
    int gid = blk * 256 + t;

    // ---- P0a: weight repack (no LDS) ----
    if (gid < 32768) {
        int j = gid & 7, lane = (gid >> 3) & 63, kt = (gid >> 9) & 7, nt = gid >> 12;
        int k = kt * 32 + (lane >> 4) * 8 + j;
        int n = nt * 16 + (lane & 15);
        p.Bp1[gid] = f2bf(p.W1[k * HIDDEN + n]);
    } else if (gid < 32768 + 6144) {
        int i2 = gid - 32768;
        int j = i2 & 7, lane = (i2 >> 3) & 63, kt = (i2 >> 9) & 3, nt = i2 >> 11;
        int k = kt * 32 + (lane >> 4) * 8 + j;
        int n = nt * 16 + (lane & 15);
        p.Bp2[i2] = (n < N_CLASSES) ? f2bf(p.W2[k * N_CLASSES + n]) : (ushort)0;
    }

    // ---- P0b: per-block bucket histogram ----
    if (t < NBUCKET) sh[t] = 0;
    __syncthreads();
    {
        int base = blk * EPB;
        for (int i = t; i < EPB; i += 256)
            atomicAdd(&sh[p.dst[base + i] >> 8], 1);
    }
    __syncthreads();
    if (t < NBUCKET) p.histT[t * 256 + blk] = sh[t];   // bucket-major
    grid.sync();

    // ---- P1: scanA over histT (196 chunks) ----
    if (blk < NBUCKET) block_scan_chunk(p.histT, p.poff, p.bsumA, NBUCKET * 256, sh);
    grid.sync();

    // ---- P2: exclusive fixup of poff ----
    if (blk < NBUCKET) block_scan_fixup(p.histT, p.poff, p.bsumA, sh);
    grid.sync();

    // ---- P3: partition edges into bucket-grouped ebuf ----
    {
        int* base = sh;            // [196]
        int* cur  = sh + 256;      // [196]
        if (t < NBUCKET) { base[t] = p.poff[t * 256 + blk]; cur[t] = 0; }
        __syncthreads();
        int eb = blk * EPB;
        for (int i = t; i < EPB; i += 256) {
            int d = p.dst[eb + i], s = p.src[eb + i];
            int bk = d >> 8;
            int pos = base[bk] + atomicAdd(&cur[bk], 1);
            p.ebuf[pos] = ((uint)d << 16) | (uint)s;
        }
    }
    grid.sync();

    // ---- P4: per-bucket degree + dinv ----
    if (blk < NBUCKET) {
        sh[t] = 0;
        __syncthreads();
        int beg = p.poff[blk * 256];
        int end = (blk < NBUCKET - 1) ? p.poff[(blk + 1) * 256] : N_EDGES;
        for (int i = beg + t; i < end; i += 256)
            atomicAdd(&sh[(p.ebuf[i] >> 16) - blk * 256], 1);
        __syncthreads();
        int node = blk * 256 + t;
        if (node < N_NODES) {
            p.deg[node] = sh[t];
            p.dinv[node] = rsqrtf((float)(sh[t] + 1));   // +1 self-loop
        } else if (node < NB_NODES * 256) {
            p.deg[node] = 0;                              // pad for scan read
        }
    }
    grid.sync();

    // ---- P5: scanA over deg ----
    if (blk < NB_NODES) block_scan_chunk(p.deg, p.rowptr, p.bsumB, N_NODES, sh);
    grid.sync();

    // ---- P6: exclusive fixup of rowptr ----
    if (blk < NB_NODES) block_scan_fixup(p.deg, p.rowptr, p.bsumB, sh);
    grid.sync();

    // ---- P7: per-bucket CSR fill ----
    if (blk < NBUCKET) {
        int* rp  = sh;             // [256]
        int* cur = sh + 256;       // [256]
        int node = blk * 256 + t;
        rp[t] = (node < N_NODES) ? p.rowptr[node] : 0;
        cur[t] = 0;
        __syncthreads();
        int beg = p.poff[blk * 256];
        int end = (blk < NBUCKET - 1) ? p.poff[(blk + 1) * 256] : N_EDGES;
        for (int i = beg + t; i < end; i += 256) {
            uint u = p.ebuf[i];
            int dl = (int)(u >> 16) - blk * 256;
            int pos = rp[dl] + atomicAdd(&cur[dl], 1);
            p.esrc[pos] = (int)(u & 0xffffu);
        }
    }
}

// ---------------- GEMM1: h1b[N,128] = bf16(x[N,256]) @ W1  (MFMA) ----------------

#define XS_STRIDE 264   // 256 + 8 bf16 pad

__global__ __launch_bounds__(256) void gemm1_mfma(const float* __restrict__ x,
                                                  const ushort* __restrict__ Bp,
                                                  ushort* __restrict__ h1b) {
    __shared__ ushort xs[64 * XS_STRIDE];   // 33792 B
    int t = threadIdx.x;
    int row0 = blockIdx.x * 64;
#pragma unroll
    for (int i = 0; i < 16; ++i) {
        int idx = t + i * 256;
        int r = idx >> 6, kg = idx & 63;
        int row = row0 + r;
        float4 v = make_float4(0.f, 0.f, 0.f, 0.f);
        if (row < N_NODES) v = *(const float4*)(x + (size_t)row * N_FEAT + kg * 4);
        ushort4 u;
        u.x = f2bf(v.x); u.y = f2bf(v.y); u.z = f2bf(v.z); u.w = f2bf(v.w);
        *(ushort4*)(&xs[r * XS_STRIDE + kg * 4]) = u;
    }
    __syncthreads();
    int lane = t & 63, w = t >> 6;
    int r = lane & 15, q = lane >> 4;
    f32x4 acc[8] = {};
    for (int kt = 0; kt < 8; ++kt) {
        bf16x8 a = *(const bf16x8*)(&xs[(w * 16 + r) * XS_STRIDE + kt * 32 + q * 8]);
#pragma unroll
        for (int nt = 0; nt < 8; ++nt) {
            bf16x8 b = *(const bf16x8*)(Bp + (((nt * 8 + kt) * 64) + lane) * 8);
            acc[nt] = __builtin_amdgcn_mfma_f32_16x16x32_bf16(a, b, acc[nt], 0, 0, 0);
        }
    }
#pragma unroll
    for (int nt = 0; nt < 8; ++nt) {
        int col = nt * 16 + r;
#pragma unroll
        for (int reg = 0; reg < 4; ++reg) {
            int row = row0 + w * 16 + q * 4 + reg;
            if (row < N_NODES) h1b[(size_t)row * HIDDEN + col] = f2bf(acc[nt][reg]);
        }
    }
}

// ---------------- layer-1 aggregation (bf16 gather, fp32 acc, unroll x4) ----------------

__global__ void agg1_g(const int* __restrict__ rowptr, const int* __restrict__ deg,
                       const int* __restrict__ esrc, const float* __restrict__ dinv,
                       const ushort* __restrict__ h1b, const float* __restrict__ b1,
                       ushort* __restrict__ hagb) {
    int w = threadIdx.x >> 6, lane = threadIdx.x & 63;
    int v = blockIdx.x * 4 + w;
    if (v >= N_NODES) return;
    int beg = rowptr[v], d = deg[v];
    float dv = dinv[v];
    uint hv = *(const uint*)(h1b + (size_t)v * HIDDEN + lane * 2);
    float ax = bflo(hv) * dv * dv, ay = bfhi(hv) * dv * dv;
    int e_l = (lane < d) ? esrc[beg + lane] : 0;
    float w_l = (lane < d) ? dinv[e_l] : 0.f;
    int dm = min(d, 64);
    int i = 0;
    for (; i + 4 <= dm; i += 4) {
        int s0 = __shfl(e_l, i + 0, 64);
        int s1 = __shfl(e_l, i + 1, 64);
        int s2 = __shfl(e_l, i + 2, 64);
        int s3 = __shfl(e_l, i + 3, 64);
        float g0 = __shfl(w_l, i + 0, 64) * dv;
        float g1 = __shfl(w_l, i + 1, 64) * dv;
        float g2 = __shfl(w_l, i + 2, 64) * dv;
        float g3 = __shfl(w_l, i + 3, 64) * dv;
        uint h0 = *(const uint*)(h1b + (size_t)s0 * HIDDEN + lane * 2);
        uint h1 = *(const uint*)(h1b + (size_t)s1 * HIDDEN + lane * 2);
        uint h2 = *(const uint*)(h1b + (size_t)s2 * HIDDEN + lane * 2);
        uint h3 = *(const uint*)(h1b + (size_t)s3 * HIDDEN + lane * 2);
        ax = fmaf(bflo(h0), g0, ax); ay = fmaf(bfhi(h0), g0, ay);
        ax = fmaf(bflo(h1), g1, ax); ay = fmaf(bfhi(h1), g1, ay);
        ax = fmaf(bflo(h2), g2, ax); ay = fmaf(bfhi(h2), g2, ay);
        ax = fmaf(bflo(h3), g3, ax); ay = fmaf(bfhi(h3), g3, ay);
    }
    for (; i < dm; ++i) {
        int s = __shfl(e_l, i, 64);
        float g = __shfl(w_l, i, 64) * dv;
        uint hs = *(const uint*)(h1b + (size_t)s * HIDDEN + lane * 2);
        ax = fmaf(bflo(hs), g, ax);
        ay = fmaf(bfhi(hs), g, ay);
    }
    for (i = 64; i < d; ++i) {           // rare (deg ~ Poisson(16))
        int s = esrc[beg + i];
        float g = dinv[s] * dv;
        uint hs = *(const uint*)(h1b + (size_t)s * HIDDEN + lane * 2);
        ax = fmaf(bflo(hs), g, ax);
        ay = fmaf(bfhi(hs), g, ay);
    }
    float2 bb = ((const float2*)b1)[lane];
    ax += bb.x; ay += bb.y;
    ax = ax > 0.f ? ax : 0.f;
    ay = ay > 0.f ? ay : 0.f;
    uint o = ((uint)f2bf(ay) << 16) | (uint)f2bf(ax);
    *(uint*)(hagb + (size_t)v * HIDDEN + lane * 2) = o;
}

// ---------------- GEMM2: h2b[N,H2S] = hagb[N,128] @ W2  (MFMA, padded rows) ----------------

__global__ __launch_bounds__(256) void gemm2_mfma(const ushort* __restrict__ hagb,
                                                  const ushort* __restrict__ Bp,
                                                  ushort* __restrict__ h2b) {
    int t = threadIdx.x;
    int lane = t & 63, w = t >> 6;
    int r = lane & 15, q = lane >> 4;
    int row0 = blockIdx.x * 64;
    int arow = row0 + w * 16 + r;            // rows < ROWS_PAD, buffer padded
    f32x4 acc[3] = {};
    for (int kt = 0; kt < 4; ++kt) {
        bf16x8 a = *(const bf16x8*)(hagb + (size_t)arow * HIDDEN + kt * 32 + q * 8);
#pragma unroll
        for (int nt = 0; nt < 3; ++nt) {
            bf16x8 b = *(const bf16x8*)(Bp + (((nt * 4 + kt) * 64) + lane) * 8);
            acc[nt] = __builtin_amdgcn_mfma_f32_16x16x32_bf16(a, b, acc[nt], 0, 0, 0);
        }
    }
#pragma unroll
    for (int nt = 0; nt < 3; ++nt) {
        int col = nt * 16 + r;
        if (col >= N_CLASSES) continue;
#pragma unroll
        for (int reg = 0; reg < 4; ++reg) {
            int row = row0 + w * 16 + q * 4 + reg;
            if (row < N_NODES) h2b[(size_t)row * H2S + col] = f2bf(acc[nt][reg]);
        }
    }
}

// ---------------- layer-2 aggregation + bias + log_softmax (2 nodes/wave) ----------------

__global__ void agg2_lsm(const int* __restrict__ rowptr, const int* __restrict__ deg,
                         const int* __restrict__ esrc, const float* __restrict__ dinv,
                         const ushort* __restrict__ h2b, const float* __restrict__ b2,
                         float* __restrict__ out) {
    int t = threadIdx.x;
    int w = t >> 6, lane = t & 63;
    int half = lane >> 5, l = lane & 31;
    int v = blockIdx.x * 8 + w * 2 + half;   // grid: v < N_NODES always
    int beg = rowptr[v], d = deg[v];
    float dv = dinv[v];
    float ax = 0.f, ay = 0.f;
    if (l < 20) {
        uint hv = *(const uint*)(h2b + (size_t)v * H2S + l * 2);
        ax = bflo(hv) * dv * dv;
        ay = bfhi(hv) * dv * dv;
    }
    int e_l = (l < d) ? esrc[beg + l] : 0;
    float w_l = (l < d) ? dinv[e_l] : 0.f;
    int dm = min(d, 32);
    int base = half * 32;
    int i = 0;
    for (; i + 4 <= dm; i += 4) {
        int s0 = __shfl(e_l, base + i + 0, 64);
        int s1 = __shfl(e_l, base + i + 1, 64);
        int s2 = __shfl(e_l, base + i + 2, 64);
        int s3 = __shfl(e_l, base + i + 3, 64);
        float g0 = __shfl(w_l, base + i + 0, 64) * dv;
        float g1 = __shfl(w_l, base + i + 1, 64) * dv;
        float g2 = __shfl(w_l, base + i + 2, 64) * dv;
        float g3 = __shfl(w_l, base + i + 3, 64) * dv;
        if (l < 20) {
            uint h0 = *(const uint*)(h2b + (size_t)s0 * H2S + l * 2);
            uint h1 = *(const uint*)(h2b + (size_t)s1 * H2S + l * 2);
            uint h2 = *(const uint*)(h2b + (size_t)s2 * H2S + l * 2);
            uint h3 = *(const uint*)(h2b + (size_t)s3 * H2S + l * 2);
            ax = fmaf(bflo(h0), g0, ax); ay = fmaf(bfhi(h0), g0, ay);
            ax = fmaf(bflo(h1), g1, ax); ay = fmaf(bfhi(h1), g1, ay);
            ax = fmaf(bflo(h2), g2, ax); ay = fmaf(bfhi(h2), g2, ay);
            ax = fmaf(bflo(h3), g3, ax); ay = fmaf(bfhi(h3), g3, ay);
        }
    }
    for (; i < dm; ++i) {
        int s = __shfl(e_l, base + i, 64);
        float g = __shfl(w_l, base + i, 64) * dv;
        if (l < 20) {
            uint hs = *(const uint*)(h2b + (size_t)s * H2S + l * 2);
            ax = fmaf(bflo(hs), g, ax);
            ay = fmaf(bfhi(hs), g, ay);
        }
    }
    for (i = 32; i < d; ++i) {               // rare tail
        int s = esrc[beg + i];
        float g = dinv[s] * dv;
        if (l < 20) {
            uint hs = *(const uint*)(h2b + (size_t)s * H2S + l * 2);
            ax = fmaf(bflo(hs), g, ax);
            ay = fmaf(bfhi(hs), g, ay);
        }
    }
    if (l < 20) {
        float2 bb = ((const float2*)b2)[l];
        ax += bb.x; ay += bb.y;
    }
    float m = (l < 20) ? fmaxf(ax, ay) : -INFINITY;
#pragma unroll
    for (int off = 16; off; off >>= 1) m = fmaxf(m, __shfl_xor(m, off, 64));
    float e = (l < 20) ? (expf(ax - m) + expf(ay - m)) : 0.f;
#pragma unroll
    for (int off = 16; off; off >>= 1) e += __shfl_xor(e, off, 64);
    float ls = logf(e);
    if (l < 20) {
        float2 o;
        o.x = ax - m - ls;
        o.y = ay - m - ls;
        ((float2*)(out + (size_t)v * N_CLASSES))[l] = o;
    }
}

// ---------------- launch ----------------

extern "C" void kernel_launch(void* const* d_in, const int* in_sizes, int n_in,
                              void* d_out, int out_size, void* d_ws, size_t ws_size,
                              hipStream_t stream) {
    const float* x  = (const float*)d_in[0];
    const int*   ei = (const int*)d_in[1];
    const float* W1 = (const float*)d_in[2];
    const float* b1 = (const float*)d_in[3];
    const float* W2 = (const float*)d_in[4];
    const float* b2 = (const float*)d_in[5];
    const int* src = ei;
    const int* dst = ei + N_EDGES;
    float* out = (float*)d_out;

    char* ws = (char*)d_ws;
    size_t off = 0;
    auto alloc = [&](size_t bytes) {
        void* p = ws + off;
        off += (bytes + 255) & ~(size_t)255;
        return p;
    };
    int*    deg    = (int*)alloc((size_t)NB_NODES * 256 * 4);
    float*  dinv   = (float*)alloc((size_t)N_NODES * 4);
    int*    histT  = (int*)alloc((size_t)NBUCKET * 256 * 4);
    int*    poff   = (int*)alloc((size_t)NBUCKET * 256 * 4);
    int*    rowptr = (int*)alloc((size_t)NB_NODES * 256 * 4);
    int*    bsumA  = (int*)alloc((size_t)256 * 4);
    int*    bsumB  = (int*)alloc((size_t)256 * 4);
    uint*   ebuf   = (uint*)alloc((size_t)N_EDGES * 4);
    int*    esrc   = (int*)alloc((size_t)N_EDGES * 4);
    ushort* Bp1    = (ushort*)alloc((size_t)32768 * 2);
    ushort* Bp2    = (ushort*)alloc((size_t)6144 * 2);
    ushort* h1b    = (ushort*)alloc((size_t)ROWS_PAD * HIDDEN * 2);
    ushort* hagb   = (ushort*)alloc((size_t)ROWS_PAD * HIDDEN * 2);
    ushort* h2b    = (ushort*)alloc((size_t)ROWS_PAD * H2S * 2);

    PP p;
    p.src = src; p.dst = dst; p.W1 = W1; p.W2 = W2;
    p.Bp1 = Bp1; p.Bp2 = Bp2;
    p.histT = histT; p.poff = poff; p.bsumA = bsumA;
    p.ebuf = ebuf; p.deg = deg; p.dinv = dinv;
    p.rowptr = rowptr; p.bsumB = bsumB; p.esrc = esrc;
    void* kargs[] = { &p };
    hipLaunchCooperativeKernel((void*)preprocess, dim3(256), dim3(256), kargs, 0, stream);

    gemm1_mfma<<<ROWS_PAD / 64, 256, 0, stream>>>(x, Bp1, h1b);
    agg1_g<<<(N_NODES + 3) / 4, 256, 0, stream>>>(rowptr, deg, esrc, dinv, h1b, b1, hagb);
    gemm2_mfma<<<ROWS_PAD / 64, 256, 0, stream>>>(hagb, Bp2, h2b);
    agg2_lsm<<<N_NODES / 8, 256, 0, stream>>>(rowptr, deg, esrc, dinv, h2b, b2, out);
}

// Round 7
// 202.334 us; speedup vs baseline: 2.0814x; 2.0814x over previous
//
#include <hip/hip_runtime.h>
#include <cstdint>

#define N_NODES 50000
#define N_EDGES 800000
#define N_FEAT 256
#define HIDDEN 128
#define N_CLASSES 40
#define NBUCKET 196         // dst >> 8
#define EPB 3125            // edges per hist/partition block (256 * 3125 = 800000)
#define ROWS_PAD 50048      // 782 * 64
#define H2S 64              // h2 row stride (ushorts) = 128 B aligned

typedef __attribute__((ext_vector_type(8))) short bf16x8;
typedef __attribute__((ext_vector_type(4))) float f32x4;

__device__ inline ushort f2bf(float f) {
    union { float f; uint u; } v; v.f = f;
    uint u = v.u;
    u += 0x7fff + ((u >> 16) & 1);   // round-to-nearest-even
    return (ushort)(u >> 16);
}
__device__ inline float bflo(uint u) {
    union { uint u; float f; } v; v.u = u << 16; return v.f;
}
__device__ inline float bfhi(uint u) {
    union { uint u; float f; } v; v.u = u & 0xffff0000u; return v.f;
}

// ---------------- 1) per-block bucket histogram + weight repack ----------------

__global__ void hist_repack(const int* __restrict__ dst, int* __restrict__ histT,
                            const float* __restrict__ W1, const float* __restrict__ W2,
                            ushort* __restrict__ Bp1, ushort* __restrict__ Bp2) {
    __shared__ int h[NBUCKET];
    int blk = blockIdx.x, t = threadIdx.x;
    int gid = blk * 256 + t;
    // repack (blocks 0..151 carry the work)
    if (gid < 32768) {
        int j = gid & 7, lane = (gid >> 3) & 63, kt = (gid >> 9) & 7, nt = gid >> 12;
        int k = kt * 32 + (lane >> 4) * 8 + j;
        int n = nt * 16 + (lane & 15);
        Bp1[gid] = f2bf(W1[k * HIDDEN + n]);
    } else if (gid < 32768 + 6144) {
        int i2 = gid - 32768;
        int j = i2 & 7, lane = (i2 >> 3) & 63, kt = (i2 >> 9) & 3, nt = i2 >> 11;
        int k = kt * 32 + (lane >> 4) * 8 + j;
        int n = nt * 16 + (lane & 15);
        Bp2[i2] = (n < N_CLASSES) ? f2bf(W2[k * N_CLASSES + n]) : (ushort)0;
    }
    // histogram
    if (t < NBUCKET) h[t] = 0;
    __syncthreads();
    int base = blk * EPB;
    for (int i = t; i < EPB; i += 256)
        atomicAdd(&h[dst[base + i] >> 8], 1);
    __syncthreads();
    if (t < NBUCKET) histT[t * 256 + blk] = h[t];   // bucket-major
}

// ---------------- 2) scan of histT -> poff (two kernels, fused block-sum scan) ----------------

__global__ void scan_a(const int* __restrict__ in, int* __restrict__ incl,
                       int* __restrict__ bsum) {
    __shared__ int s[256];
    int blk = blockIdx.x, t = threadIdx.x;
    int i = blk * 256 + t;
    s[t] = in[i];
    __syncthreads();
    for (int off = 1; off < 256; off <<= 1) {
        int t2 = 0;
        if (t >= off) t2 = s[t - off];
        __syncthreads();
        s[t] += t2;
        __syncthreads();
    }
    incl[i] = s[t];
    if (t == 255) bsum[blk] = s[255];
}

__global__ void scan_c(int* __restrict__ incl, const int* __restrict__ in,
                       const int* __restrict__ bsum) {
    // exclusive fixup; each block redundantly scans bsum[0..NBUCKET) in LDS
    __shared__ int s[256];
    int blk = blockIdx.x, t = threadIdx.x;
    s[t] = (t < NBUCKET) ? bsum[t] : 0;
    __syncthreads();
    for (int off = 1; off < 256; off <<= 1) {
        int t2 = 0;
        if (t >= off) t2 = s[t - off];
        __syncthreads();
        s[t] += t2;
        __syncthreads();
    }
    int base = (blk > 0) ? s[blk - 1] : 0;
    int i = blk * 256 + t;
    incl[i] = incl[i] - in[i] + base;
}

// ---------------- 3) partition edges into bucket-grouped ebuf ----------------

__global__ void partition_k(const int* __restrict__ src, const int* __restrict__ dst,
                            const int* __restrict__ poff, uint* __restrict__ ebuf) {
    __shared__ int base[NBUCKET];
    __shared__ int cur[NBUCKET];
    int blk = blockIdx.x, t = threadIdx.x;
    if (t < NBUCKET) { base[t] = poff[t * 256 + blk]; cur[t] = 0; }
    __syncthreads();
    int eb = blk * EPB;
    for (int i = t; i < EPB; i += 256) {
        int d = dst[eb + i], s = src[eb + i];
        int bk = d >> 8;
        int p = base[bk] + atomicAdd(&cur[bk], 1);
        ebuf[p] = ((uint)d << 16) | (uint)s;
    }
}

// ---------------- 4) per-bucket: degree + dinv + LOCAL rowptr + CSR fill (one kernel) ----------------
// rowptr[node] = poff[bucket*256] + exclusive_scan_within_bucket(deg) — no global scan needed.

__global__ void bucket_csr(const uint* __restrict__ ebuf, const int* __restrict__ poff,
                           int* __restrict__ deg, float* __restrict__ dinv,
                           int* __restrict__ rowptr, int* __restrict__ esrc) {
    __shared__ int cnt[256];
    __shared__ int s[256];
    __shared__ int exc[256];
    __shared__ int cur[256];
    int b = blockIdx.x, t = threadIdx.x;
    cnt[t] = 0;
    cur[t] = 0;
    __syncthreads();
    int beg = poff[b * 256];
    int end = (b < NBUCKET - 1) ? poff[(b + 1) * 256] : N_EDGES;
    for (int i = beg + t; i < end; i += 256)
        atomicAdd(&cnt[(ebuf[i] >> 16) & 255], 1);
    __syncthreads();
    int d = cnt[t];
    s[t] = d;
    __syncthreads();
    for (int off = 1; off < 256; off <<= 1) {
        int t2 = 0;
        if (t >= off) t2 = s[t - off];
        __syncthreads();
        s[t] += t2;
        __syncthreads();
    }
    exc[t] = s[t] - d;
    int node = b * 256 + t;
    if (node < N_NODES) {
        deg[node] = d;
        dinv[node] = rsqrtf((float)(d + 1));        // +1 self-loop
        rowptr[node] = beg + exc[t];
    }
    __syncthreads();
    for (int i = beg + t; i < end; i += 256) {
        uint u = ebuf[i];
        int dl = (int)(u >> 16) & 255;
        int pos = beg + exc[dl] + atomicAdd(&cur[dl], 1);
        esrc[pos] = (int)(u & 0xffffu);
    }
}

// ---------------- GEMM1: h1b[N,128] = bf16(x[N,256]) @ W1  (MFMA) ----------------

#define XS_STRIDE 264   // 256 + 8 bf16 pad

__global__ __launch_bounds__(256) void gemm1_mfma(const float* __restrict__ x,
                                                  const ushort* __restrict__ Bp,
                                                  ushort* __restrict__ h1b) {
    __shared__ ushort xs[64 * XS_STRIDE];   // 33792 B
    int t = threadIdx.x;
    int row0 = blockIdx.x * 64;
#pragma unroll
    for (int i = 0; i < 16; ++i) {
        int idx = t + i * 256;
        int r = idx >> 6, kg = idx & 63;
        int row = row0 + r;
        float4 v = make_float4(0.f, 0.f, 0.f, 0.f);
        if (row < N_NODES) v = *(const float4*)(x + (size_t)row * N_FEAT + kg * 4);
        ushort4 u;
        u.x = f2bf(v.x); u.y = f2bf(v.y); u.z = f2bf(v.z); u.w = f2bf(v.w);
        *(ushort4*)(&xs[r * XS_STRIDE + kg * 4]) = u;
    }
    __syncthreads();
    int lane = t & 63, w = t >> 6;
    int r = lane & 15, q = lane >> 4;
    f32x4 acc[8] = {};
    for (int kt = 0; kt < 8; ++kt) {
        bf16x8 a = *(const bf16x8*)(&xs[(w * 16 + r) * XS_STRIDE + kt * 32 + q * 8]);
#pragma unroll
        for (int nt = 0; nt < 8; ++nt) {
            bf16x8 b = *(const bf16x8*)(Bp + (((nt * 8 + kt) * 64) + lane) * 8);
            acc[nt] = __builtin_amdgcn_mfma_f32_16x16x32_bf16(a, b, acc[nt], 0, 0, 0);
        }
    }
#pragma unroll
    for (int nt = 0; nt < 8; ++nt) {
        int col = nt * 16 + r;
#pragma unroll
        for (int reg = 0; reg < 4; ++reg) {
            int row = row0 + w * 16 + q * 4 + reg;
            if (row < N_NODES) h1b[(size_t)row * HIDDEN + col] = f2bf(acc[nt][reg]);
        }
    }
}

// ---------------- layer-1 aggregation: 2 edges/wave-iter, halves own edges ----------------
// wave = 1 node; half h (32 lanes) handles edges i+h; lane l<32 covers feats 4l..4l+3 (uint2).

__global__ void agg1_g(const int* __restrict__ rowptr, const int* __restrict__ deg,
                       const int* __restrict__ esrc, const float* __restrict__ dinv,
                       const ushort* __restrict__ h1b, const float* __restrict__ b1,
                       ushort* __restrict__ hagb) {
    int w = threadIdx.x >> 6, lane = threadIdx.x & 63;
    int v = blockIdx.x * 4 + w;
    if (v >= N_NODES) return;
    int half = lane >> 5, l = lane & 31;
    int beg = rowptr[v], d = deg[v];
    float dv = dinv[v];
    float ax = 0.f, ay = 0.f, az = 0.f, aw = 0.f;
    if (half == 0) {    // self-loop term counted once
        uint2 hv = *(const uint2*)(h1b + (size_t)v * HIDDEN + l * 4);
        float dd = dv * dv;
        ax = bflo(hv.x) * dd; ay = bfhi(hv.x) * dd;
        az = bflo(hv.y) * dd; aw = bfhi(hv.y) * dd;
    }
    int e_l = (lane < d) ? esrc[beg + lane] : 0;
    float w_l = (lane < d) ? dinv[e_l] : 0.f;   // 0 weight for lanes >= d: invalid edges vanish
    int dm = min(d, 64);
    int i = 0;
    for (; i + 4 <= dm; i += 4) {
        int s0 = __shfl(e_l, i + half, 64);
        int s1 = __shfl(e_l, i + 2 + half, 64);
        float g0 = __shfl(w_l, i + half, 64) * dv;
        float g1 = __shfl(w_l, i + 2 + half, 64) * dv;
        uint2 h0 = *(const uint2*)(h1b + (size_t)s0 * HIDDEN + l * 4);
        uint2 h1v = *(const uint2*)(h1b + (size_t)s1 * HIDDEN + l * 4);
        ax = fmaf(bflo(h0.x), g0, ax);  ay = fmaf(bfhi(h0.x), g0, ay);
        az = fmaf(bflo(h0.y), g0, az);  aw = fmaf(bfhi(h0.y), g0, aw);
        ax = fmaf(bflo(h1v.x), g1, ax); ay = fmaf(bfhi(h1v.x), g1, ay);
        az = fmaf(bflo(h1v.y), g1, az); aw = fmaf(bfhi(h1v.y), g1, aw);
    }
    for (; i < dm; i += 2) {          // pair tail (g=0 guards odd counts)
        int s0 = __shfl(e_l, i + half, 64);
        float g0 = __shfl(w_l, i + half, 64) * dv;
        uint2 h0 = *(const uint2*)(h1b + (size_t)s0 * HIDDEN + l * 4);
        ax = fmaf(bflo(h0.x), g0, ax); ay = fmaf(bfhi(h0.x), g0, ay);
        az = fmaf(bflo(h0.y), g0, az); aw = fmaf(bfhi(h0.y), g0, aw);
    }
    for (int j = 64 + half; j < d; j += 2) {   // rare deg>64 tail, halves alternate
        int s = esrc[beg + j];
        float g = dinv[s] * dv;
        uint2 hs = *(const uint2*)(h1b + (size_t)s * HIDDEN + l * 4);
        ax = fmaf(bflo(hs.x), g, ax); ay = fmaf(bfhi(hs.x), g, ay);
        az = fmaf(bflo(hs.y), g, az); aw = fmaf(bfhi(hs.y), g, aw);
    }
    // combine halves
    ax += __shfl_xor(ax, 32, 64);
    ay += __shfl_xor(ay, 32, 64);
    az += __shfl_xor(az, 32, 64);
    aw += __shfl_xor(aw, 32, 64);
    if (half == 0) {
        float4 bb = ((const float4*)b1)[l];
        ax += bb.x; ay += bb.y; az += bb.z; aw += bb.w;
        ax = ax > 0.f ? ax : 0.f;
        ay = ay > 0.f ? ay : 0.f;
        az = az > 0.f ? az : 0.f;
        aw = aw > 0.f ? aw : 0.f;
        uint2 o;
        o.x = ((uint)f2bf(ay) << 16) | (uint)f2bf(ax);
        o.y = ((uint)f2bf(aw) << 16) | (uint)f2bf(az);
        *(uint2*)(hagb + (size_t)v * HIDDEN + l * 4) = o;
    }
}

// ---------------- GEMM2: h2b[N,H2S] = hagb[N,128] @ W2  (MFMA, padded rows) ----------------

__global__ __launch_bounds__(256) void gemm2_mfma(const ushort* __restrict__ hagb,
                                                  const ushort* __restrict__ Bp,
                                                  ushort* __restrict__ h2b) {
    int t = threadIdx.x;
    int lane = t & 63, w = t >> 6;
    int r = lane & 15, q = lane >> 4;
    int row0 = blockIdx.x * 64;
    int arow = row0 + w * 16 + r;            // rows < ROWS_PAD, buffer padded
    f32x4 acc[3] = {};
    for (int kt = 0; kt < 4; ++kt) {
        bf16x8 a = *(const bf16x8*)(hagb + (size_t)arow * HIDDEN + kt * 32 + q * 8);
#pragma unroll
        for (int nt = 0; nt < 3; ++nt) {
            bf16x8 b = *(const bf16x8*)(Bp + (((nt * 4 + kt) * 64) + lane) * 8);
            acc[nt] = __builtin_amdgcn_mfma_f32_16x16x32_bf16(a, b, acc[nt], 0, 0, 0);
        }
    }
#pragma unroll
    for (int nt = 0; nt < 3; ++nt) {
        int col = nt * 16 + r;
        if (col >= N_CLASSES) continue;
#pragma unroll
        for (int reg = 0; reg < 4; ++reg) {
            int row = row0 + w * 16 + q * 4 + reg;
            if (row < N_NODES) h2b[(size_t)row * H2S + col] = f2bf(acc[nt][reg]);
        }
    }
}

// ---------------- layer-2 aggregation + bias + log_softmax (2 nodes/wave) ----------------

__global__ void agg2_lsm(const int* __restrict__ rowptr, const int* __restrict__ deg,
                         const int* __restrict__ esrc, const float* __restrict__ dinv,
                         const ushort* __restrict__ h2b, const float* __restrict__ b2,
                         float* __restrict__ out) {
    int t = threadIdx.x;
    int w = t >> 6, lane = t & 63;
    int half = lane >> 5, l = lane & 31;
    int v = blockIdx.x * 8 + w * 2 + half;   // grid: v < N_NODES always
    int beg = rowptr[v], d = deg[v];
    float dv = dinv[v];
    float ax = 0.f, ay = 0.f;
    if (l < 20) {
        uint hv = *(const uint*)(h2b + (size_t)v * H2S + l * 2);
        ax = bflo(hv) * dv * dv;
        ay = bfhi(hv) * dv * dv;
    }
    int e_l = (l < d) ? esrc[beg + l] : 0;
    float w_l = (l < d) ? dinv[e_l] : 0.f;
    int dm = min(d, 32);
    int base = half * 32;
    int i = 0;
    for (; i + 4 <= dm; i += 4) {
        int s0 = __shfl(e_l, base + i + 0, 64);
        int s1 = __shfl(e_l, base + i + 1, 64);
        int s2 = __shfl(e_l, base + i + 2, 64);
        int s3 = __shfl(e_l, base + i + 3, 64);
        float g0 = __shfl(w_l, base + i + 0, 64) * dv;
        float g1 = __shfl(w_l, base + i + 1, 64) * dv;
        float g2 = __shfl(w_l, base + i + 2, 64) * dv;
        float g3 = __shfl(w_l, base + i + 3, 64) * dv;
        if (l < 20) {
            uint h0 = *(const uint*)(h2b + (size_t)s0 * H2S + l * 2);
            uint h1 = *(const uint*)(h2b + (size_t)s1 * H2S + l * 2);
            uint h2 = *(const uint*)(h2b + (size_t)s2 * H2S + l * 2);
            uint h3 = *(const uint*)(h2b + (size_t)s3 * H2S + l * 2);
            ax = fmaf(bflo(h0), g0, ax); ay = fmaf(bfhi(h0), g0, ay);
            ax = fmaf(bflo(h1), g1, ax); ay = fmaf(bfhi(h1), g1, ay);
            ax = fmaf(bflo(h2), g2, ax); ay = fmaf(bfhi(h2), g2, ay);
            ax = fmaf(bflo(h3), g3, ax); ay = fmaf(bfhi(h3), g3, ay);
        }
    }
    for (; i < dm; ++i) {
        int s = __shfl(e_l, base + i, 64);
        float g = __shfl(w_l, base + i, 64) * dv;
        if (l < 20) {
            uint hs = *(const uint*)(h2b + (size_t)s * H2S + l * 2);
            ax = fmaf(bflo(hs), g, ax);
            ay = fmaf(bfhi(hs), g, ay);
        }
    }
    for (i = 32; i < d; ++i) {               // rare tail
        int s = esrc[beg + i];
        float g = dinv[s] * dv;
        if (l < 20) {
            uint hs = *(const uint*)(h2b + (size_t)s * H2S + l * 2);
            ax = fmaf(bflo(hs), g, ax);
            ay = fmaf(bfhi(hs), g, ay);
        }
    }
    if (l < 20) {
        float2 bb = ((const float2*)b2)[l];
        ax += bb.x; ay += bb.y;
    }
    float m = (l < 20) ? fmaxf(ax, ay) : -INFINITY;
#pragma unroll
    for (int off = 16; off; off >>= 1) m = fmaxf(m, __shfl_xor(m, off, 64));
    float e = (l < 20) ? (expf(ax - m) + expf(ay - m)) : 0.f;
#pragma unroll
    for (int off = 16; off; off >>= 1) e += __shfl_xor(e, off, 64);
    float ls = logf(e);
    if (l < 20) {
        float2 o;
        o.x = ax - m - ls;
        o.y = ay - m - ls;
        ((float2*)(out + (size_t)v * N_CLASSES))[l] = o;
    }
}

// ---------------- launch ----------------

extern "C" void kernel_launch(void* const* d_in, const int* in_sizes, int n_in,
                              void* d_out, int out_size, void* d_ws, size_t ws_size,
                              hipStream_t stream) {
    const float* x  = (const float*)d_in[0];
    const int*   ei = (const int*)d_in[1];
    const float* W1 = (const float*)d_in[2];
    const float* b1 = (const float*)d_in[3];
    const float* W2 = (const float*)d_in[4];
    const float* b2 = (const float*)d_in[5];
    const int* src = ei;
    const int* dst = ei + N_EDGES;
    float* out = (float*)d_out;

    char* ws = (char*)d_ws;
    size_t off = 0;
    auto alloc = [&](size_t bytes) {
        void* p = ws + off;
        off += (bytes + 255) & ~(size_t)255;
        return p;
    };
    int*    deg    = (int*)alloc((size_t)N_NODES * 4);
    float*  dinv   = (float*)alloc((size_t)N_NODES * 4);
    int*    histT  = (int*)alloc((size_t)NBUCKET * 256 * 4);
    int*    poff   = (int*)alloc((size_t)NBUCKET * 256 * 4);
    int*    rowptr = (int*)alloc((size_t)N_NODES * 4);
    int*    bsumA  = (int*)alloc((size_t)256 * 4);
    uint*   ebuf   = (uint*)alloc((size_t)N_EDGES * 4);
    int*    esrc   = (int*)alloc((size_t)N_EDGES * 4);
    ushort* Bp1    = (ushort*)alloc((size_t)32768 * 2);
    ushort* Bp2    = (ushort*)alloc((size_t)6144 * 2);
    ushort* h1b    = (ushort*)alloc((size_t)ROWS_PAD * HIDDEN * 2);
    ushort* hagb   = (ushort*)alloc((size_t)ROWS_PAD * HIDDEN * 2);
    ushort* h2b    = (ushort*)alloc((size_t)ROWS_PAD * H2S * 2);

    // --- preprocessing: 5 kernels, no global atomics, no memsets ---
    hist_repack<<<256, 256, 0, stream>>>(dst, histT, W1, W2, Bp1, Bp2);
    scan_a<<<NBUCKET, 256, 0, stream>>>(histT, poff, bsumA);
    scan_c<<<NBUCKET, 256, 0, stream>>>(poff, histT, bsumA);
    partition_k<<<256, 256, 0, stream>>>(src, dst, poff, ebuf);
    bucket_csr<<<NBUCKET, 256, 0, stream>>>(ebuf, poff, deg, dinv, rowptr, esrc);

    // --- model: 4 kernels ---
    gemm1_mfma<<<ROWS_PAD / 64, 256, 0, stream>>>(x, Bp1, h1b);
    agg1_g<<<(N_NODES + 3) / 4, 256, 0, stream>>>(rowptr, deg, esrc, dinv, h1b, b1, hagb);
    gemm2_mfma<<<ROWS_PAD / 64, 256, 0, stream>>>(hagb, Bp2, h2b);
    agg2_lsm<<<N_NODES / 8, 256, 0, stream>>>(rowptr, deg, esrc, dinv, h2b, b2, out);
}